// Round 2
// baseline (106.464 us; speedup 1.0000x reference)
//
#include <hip/hip_runtime.h>
#include <hip/hip_bf16.h>
#include <stdint.h>

typedef __bf16 bf16_t;
typedef bf16_t bf16x8 __attribute__((ext_vector_type(8)));
typedef float f32x16 __attribute__((ext_vector_type(16)));
typedef float fvec4 __attribute__((ext_vector_type(4)));
typedef unsigned int u32x4v __attribute__((ext_vector_type(4)));

#define LEN 2048
#define DIM 64
#define QBLK 128
#define KVB 64

// log2(e)/8 and log2(e)/16 : score = exp(2c*dot - c*sq_i - c*sq_j), c = 1/16
#define C_L8  0.18033688011112043f
#define C_L16 0.09016844005556021f

__device__ __forceinline__ float fexp2(float x) {
#if __has_builtin(__builtin_amdgcn_exp2f)
  return __builtin_amdgcn_exp2f(x);
#else
  return exp2f(x);
#endif
}

__device__ __forceinline__ unsigned pk2(float lo, float hi) {
  union { bf16_t h; unsigned short u; } a, b;
  a.h = (bf16_t)lo; b.h = (bf16_t)hi;
  return (unsigned)a.u | ((unsigned)b.u << 16);
}

// swizzled byte address within a [64 rows][128 B] LDS tile (b128 bank-floor)
__device__ __forceinline__ int sw(int row, int byte) {
  return row * 128 + (byte ^ ((row & 7) << 4));
}

__global__ __launch_bounds__(512, 2) void soft_attn(
    const float* __restrict__ q, const float* __restrict__ v,
    float* __restrict__ out) {
  // smem layout: Kbuf[2][8192] | Vt[2][8192] | wk[2][64]
  __shared__ __align__(16) char smem[33280];

  const int tid    = threadIdx.x;
  const int lane   = tid & 63;
  const int wave   = tid >> 6;
  const int rg     = wave & 3;   // q-row group (32 rows each)
  const int parity = wave >> 2;  // j-tile parity (K-split)
  const int tp     = tid & 255;  // thread-in-parity
  const int g      = lane >> 5;  // wave half
  const int nn     = lane & 31;

  // XCD-aware swizzle: 256 blocks = 8 XCDs * 32 contiguous wg -> 2 heads/XCD
  const int wg = ((blockIdx.x & 7) << 5) | (blockIdx.x >> 3);
  const int bh = wg >> 4;
  const int qb = wg & 15;

  const float* qh = q + (size_t)bh * LEN * DIM;
  const float* vh = v + (size_t)bh * LEN * DIM;

  char*  kbufp = smem + parity * 8192;
  char*  vbufp = smem + 16384 + parity * 8192;
  float* wkp   = (float*)(smem + 32768) + parity * 64;

  // ---- Q prologue: frags in registers (B-operand layout), hq = c*sq_i*log2e
  const int qrow = qb * QBLK + rg * 32 + nn;
  bf16x8 qf[4];
  float sq = 0.f;
  {
    const float* qp = qh + (size_t)qrow * DIM;
#pragma unroll
    for (int kc = 0; kc < 4; ++kc) {
      const int d0 = kc * 16 + g * 8;
      fvec4 x = *(const fvec4*)(qp + d0);
      fvec4 y = *(const fvec4*)(qp + d0 + 4);
      bf16x8 t;
#pragma unroll
      for (int e = 0; e < 4; ++e) {
        bf16_t h0 = (bf16_t)x[e]; t[e]     = h0; float f0 = (float)h0; sq += f0 * f0;
        bf16_t h1 = (bf16_t)y[e]; t[e + 4] = h1; float f1 = (float)h1; sq += f1 * f1;
      }
      qf[kc] = t;
    }
  }
  sq += __shfl_xor(sq, 32);
  const float hq = sq * C_L16;

  f32x16 acc0 = {};
  f32x16 acc1 = {};

  for (int it = 0; it < 16; ++it) {
    const int jt = it * 2 + parity;
    const float* kg = qh + (size_t)jt * KVB * DIM;
    const float* vg = vh + (size_t)jt * KVB * DIM;

    __syncthreads();

    // ---- stage K tile (f32 -> bf16, swizzled) + w_j = exp(-c*sq_j)
#pragma unroll
    for (int s = 0; s < 2; ++s) {
      const int c  = tp + 256 * s;
      const int j  = c >> 3;
      const int d0 = (c & 7) * 8;
      fvec4 x = *(const fvec4*)(kg + j * DIM + d0);
      fvec4 y = *(const fvec4*)(kg + j * DIM + d0 + 4);
      bf16x8 t; float p = 0.f;
#pragma unroll
      for (int e = 0; e < 4; ++e) {
        bf16_t h0 = (bf16_t)x[e]; t[e]     = h0; float f0 = (float)h0; p += f0 * f0;
        bf16_t h1 = (bf16_t)y[e]; t[e + 4] = h1; float f1 = (float)h1; p += f1 * f1;
      }
      *(bf16x8*)(kbufp + sw(j, d0 * 2)) = t;
      p += __shfl_xor(p, 1);
      p += __shfl_xor(p, 2);
      p += __shfl_xor(p, 4);
      if ((lane & 7) == 0) wkp[j] = fexp2(-p * C_L16);
    }

    __syncthreads();

    // ---- issue V global loads early (hide under QK^T)
    float vl[2][8];
    const int vd = tp & 63;
    const int vw = tp >> 6;
#pragma unroll
    for (int s = 0; s < 2; ++s) {
      const int j0 = vw * 8 + 32 * s;
      const float* vp = vg + j0 * DIM + vd;
#pragma unroll
      for (int r = 0; r < 8; ++r) vl[s][r] = vp[r * DIM];
    }

    // ---- swapped QK^T (mfma(K,Q) -> S~^T), exp2, pack, permlane exchange
    bf16x8 af[4];
#pragma unroll
    for (int jsub = 0; jsub < 2; ++jsub) {
      f32x16 t = {};
#pragma unroll
      for (int kc = 0; kc < 4; ++kc) {
        bf16x8 kf = *(const bf16x8*)(kbufp + sw(jsub * 32 + nn, kc * 32 + g * 16));
        t = __builtin_amdgcn_mfma_f32_32x32x16_bf16(kf, qf[kc], t, 0, 0, 0);
      }
      unsigned P[8];
#pragma unroll
      for (int e = 0; e < 8; ++e) {
        float s0 = fexp2(__builtin_fmaf(t[2 * e],     C_L8, -hq));
        float s1 = fexp2(__builtin_fmaf(t[2 * e + 1], C_L8, -hq));
        P[e] = pk2(s0, s1);
      }
      // lane-half exchange: vdst=[vdstL|vsrcL], vsrc=[vdstU|vsrcU]
      // -> lower lanes end with P0L,P1L,P0U,P1U; upper with P2L,P3L,P2U,P3U
      asm volatile("v_permlane32_swap_b32 %0, %1" : "+v"(P[0]), "+v"(P[2]));
      asm volatile("v_permlane32_swap_b32 %0, %1" : "+v"(P[1]), "+v"(P[3]));
      asm volatile("v_permlane32_swap_b32 %0, %1" : "+v"(P[4]), "+v"(P[6]));
      asm volatile("v_permlane32_swap_b32 %0, %1" : "+v"(P[5]), "+v"(P[7]));
      u32x4v f0v = { P[0], P[1], P[2], P[3] };
      u32x4v f1v = { P[4], P[5], P[6], P[7] };
      af[jsub * 2]     = __builtin_bit_cast(bf16x8, f0v);
      af[jsub * 2 + 1] = __builtin_bit_cast(bf16x8, f1v);
    }

    // ---- scale V by w_j, write transposed V~^T[d][j] (swizzled)
#pragma unroll
    for (int s = 0; s < 2; ++s) {
      const int j0 = vw * 8 + 32 * s;
      bf16x8 t;
#pragma unroll
      for (int r = 0; r < 8; ++r) {
        float w = wkp[j0 + r];
        t[r] = (bf16_t)(vl[s][r] * w);
      }
      *(bf16x8*)(vbufp + sw(vd, j0 * 2)) = t;
    }

    __syncthreads();

    // ---- PV: acc += S~ * V~
#pragma unroll
    for (int kc = 0; kc < 4; ++kc) {
      bf16x8 v0 = *(const bf16x8*)(vbufp + sw(nn,      kc * 32 + g * 16));
      bf16x8 v1 = *(const bf16x8*)(vbufp + sw(32 + nn, kc * 32 + g * 16));
      acc0 = __builtin_amdgcn_mfma_f32_32x32x16_bf16(af[kc], v0, acc0, 0, 0, 0);
      acc1 = __builtin_amdgcn_mfma_f32_32x32x16_bf16(af[kc], v1, acc1, 0, 0, 0);
    }
  }

  // ---- combine the two j-parities, write out
  __syncthreads();
  float* xb = (float*)smem + rg * 2048;
  if (parity == 1) {
#pragma unroll
    for (int r = 0; r < 16; ++r) {
      xb[r * 64 + lane]        = acc0[r];
      xb[(16 + r) * 64 + lane] = acc1[r];
    }
  }
  __syncthreads();
  if (parity == 0) {
    float* op = out + ((size_t)bh * LEN + qb * QBLK + rg * 32) * DIM;
#pragma unroll
    for (int r = 0; r < 16; ++r) {
      const int row = (r & 3) + 8 * (r >> 2) + 4 * g;
      op[(size_t)row * DIM + nn]      = acc0[r] + xb[r * 64 + lane];
      op[(size_t)row * DIM + 32 + nn] = acc1[r] + xb[(16 + r) * 64 + lane];
    }
  }
}

extern "C" void kernel_launch(void* const* d_in, const int* in_sizes, int n_in,
                              void* d_out, int out_size, void* d_ws, size_t ws_size,
                              hipStream_t stream) {
  const float* q = (const float*)d_in[0];
  const float* v = (const float*)d_in[1];
  float* out = (float*)d_out;
  (void)in_sizes; (void)n_in; (void)d_ws; (void)ws_size; (void)out_size;
  soft_attn<<<dim3(256), dim3(512), 0, stream>>>(q, v, out);
}

// Round 4
// 95.074 us; speedup vs baseline: 1.1198x; 1.1198x over previous
//
#include <hip/hip_runtime.h>
#include <hip/hip_bf16.h>
#include <stdint.h>

typedef __bf16 bf16_t;
typedef bf16_t bf16x8 __attribute__((ext_vector_type(8)));
typedef float f32x16 __attribute__((ext_vector_type(16)));
typedef float fvec4 __attribute__((ext_vector_type(4)));
typedef unsigned int u32x4v __attribute__((ext_vector_type(4)));

#define LEN 2048
#define DIM 64
#define NH  16

// c = 1/(2*sqrt(64)) = 1/16;  C_L8 = 2c*log2(e), C_L16 = c*log2(e)
#define C_L8  0.18033688011112043f
#define C_L16 0.09016844005556021f

__device__ __forceinline__ float fexp2(float x) {
#if __has_builtin(__builtin_amdgcn_exp2f)
  return __builtin_amdgcn_exp2f(x);
#else
  return exp2f(x);
#endif
}

__device__ __forceinline__ unsigned pk2(float lo, float hi) {
  union { bf16_t h; unsigned short u; } a, b;
  a.h = (bf16_t)lo; b.h = (bf16_t)hi;
  return (unsigned)a.u | ((unsigned)b.u << 16);
}

__device__ __forceinline__ void glds16(const void* g, void* l) {
  __builtin_amdgcn_global_load_lds(
      (const __attribute__((address_space(1))) void*)g,
      (__attribute__((address_space(3))) void*)l, 16, 0, 0);
}

// swizzled byte offsets: K tile [128 rows][128B], V tile [64 rows][256B]
__device__ __forceinline__ int swk(int row, int b) {
  return row * 128 + (b ^ ((row & 7) << 4));
}
__device__ __forceinline__ int swv(int row, int b) {
  return row * 256 + (b ^ ((row & 7) << 4));
}

// ---------------- pre-pass: K~=bf16(q), Vt~[h][d][j]=bf16(w_j*v), hq ----------
__global__ __launch_bounds__(256) void prepass(
    const float* __restrict__ q, const float* __restrict__ v,
    bf16_t* __restrict__ kb, bf16_t* __restrict__ vt, float* __restrict__ sqw) {
  __shared__ float wlds[64];
  const int b = blockIdx.x;          // 512 = 16 heads * 32 j-blocks(64)
  const int h = b >> 5, jb = b & 31;
  const int t = threadIdx.x;
  const float* qh = q + ((size_t)h * LEN + jb * 64) * DIM;
  const float* vh = v + ((size_t)h * LEN + jb * 64) * DIM;

  // K part: thread t handles row j=t>>2, dims d0..d0+15
  {
    const int j = t >> 2, d0 = (t & 3) * 16;
    const float* qp = qh + j * DIM + d0;
    float s = 0.f;
    bf16x8 o0, o1;
#pragma unroll
    for (int e = 0; e < 8; ++e) {
      bf16_t hh = (bf16_t)qp[e]; o0[e] = hh; float f = (float)hh; s += f * f;
    }
#pragma unroll
    for (int e = 0; e < 8; ++e) {
      bf16_t hh = (bf16_t)qp[8 + e]; o1[e] = hh; float f = (float)hh; s += f * f;
    }
    bf16_t* kp = kb + ((size_t)h * LEN + jb * 64 + j) * DIM + d0;
    *(bf16x8*)kp = o0;
    *(bf16x8*)(kp + 8) = o1;
    s += __shfl_xor(s, 1);
    s += __shfl_xor(s, 2);
    if ((t & 3) == 0) {
      wlds[j] = fexp2(-s * C_L16);
      sqw[h * LEN + jb * 64 + j] = s * C_L16;
    }
  }
  __syncthreads();
  // V part: thread t handles dim d=t&63, rows jg*16..+16 (transposed write)
  {
    const int d = t & 63, jg = t >> 6;
    float vv[16];
#pragma unroll
    for (int e = 0; e < 16; ++e) vv[e] = vh[(jg * 16 + e) * DIM + d];
    bf16x8 o0, o1;
#pragma unroll
    for (int e = 0; e < 8; ++e)  o0[e] = (bf16_t)(vv[e] * wlds[jg * 16 + e]);
#pragma unroll
    for (int e = 0; e < 8; ++e)  o1[e] = (bf16_t)(vv[8 + e] * wlds[jg * 16 + 8 + e]);
    bf16_t* vp = vt + ((size_t)h * DIM + d) * LEN + jb * 64 + jg * 16;
    *(bf16x8*)vp = o0;
    *(bf16x8*)(vp + 8) = o1;
  }
}

// ---------------- main kernel: 512 blocks x 512 thr, 2 blocks/CU --------------
__global__ __launch_bounds__(512, 4) void soft_attn_main(
    const bf16_t* __restrict__ kb, const bf16_t* __restrict__ vt,
    const float* __restrict__ sqw, float* __restrict__ out) {
  // kbuf[2][128][128B] @0..32K | vbuf[2][64][256B] @32K..64K ; epilogue reuses
  __shared__ __align__(16) char smem[65536];

  const int tid  = threadIdx.x;
  const int lane = tid & 63;
  const int wave = tid >> 6;
  const int rg   = wave & 1;   // q row-group (32 rows)
  const int par  = wave >> 1;  // j parity (4-way split of the 128-j tile)
  const int g    = lane >> 5;
  const int nn   = lane & 31;

  // XCD swizzle: 512 blocks = 8 XCDs * 64 contiguous -> 2 heads per XCD
  const int b  = blockIdx.x;
  const int wg = ((b & 7) << 6) | (b >> 3);
  const int bh = wg >> 5;
  const int qb = wg & 31;

  const bf16_t* kh  = kb + (size_t)bh * LEN * DIM;
  const bf16_t* vth = vt + (size_t)bh * DIM * LEN;

  // Q frags (B-operand) + hq, straight from precomputed arrays
  const int qrow = qb * 64 + rg * 32 + nn;
  bf16x8 qf[4];
  {
    const bf16_t* qp = kh + (size_t)qrow * DIM;
#pragma unroll
    for (int kc = 0; kc < 4; ++kc)
      qf[kc] = *(const bf16x8*)(qp + kc * 16 + g * 8);
  }
  const float hq = sqw[bh * LEN + qrow];

  // staging source addresses (pre-swizzled global so linear LDS = swizzled)
  // K chunk ck=wave*2+s: rows ck*8+(l>>3); byte (l&7)*16 ^ ((l>>3)<<4)
  const bf16_t* ksrc[2];
  const bf16_t* vsrc[2];
#pragma unroll
  for (int s = 0; s < 2; ++s) {
    const int krow = wave * 16 + s * 8 + (lane >> 3);
    const int kby  = ((lane & 7) * 16) ^ ((lane >> 3) << 4);
    ksrc[s] = kh + (size_t)krow * DIM + (kby >> 1);
    const int vrow = wave * 8 + s * 4 + (lane >> 4);
    const int vby  = ((lane & 15) * 16) ^ ((vrow & 7) << 4);
    vsrc[s] = vth + (size_t)vrow * LEN + (vby >> 1);
  }
  char* kdst = smem + wave * 2048;
  char* vdst = smem + 32768 + wave * 2048;

  f32x16 acc0 = {};
  f32x16 acc1 = {};

  // prologue: stage tile 0 into buf 0
#pragma unroll
  for (int s = 0; s < 2; ++s) {
    glds16(ksrc[s], kdst + s * 1024);
    glds16(vsrc[s], vdst + s * 1024);
  }
  __syncthreads();

  int buf = 0;
  for (int it = 0; it < 16; ++it) {
    // stage next tile into the other buffer (hidden under compute)
    if (it + 1 < 16) {
      const int nb = buf ^ 1;
#pragma unroll
      for (int s = 0; s < 2; ++s) {
        glds16(ksrc[s] + (size_t)(it + 1) * 128 * DIM, kdst + nb * 16384 + s * 1024);
        glds16(vsrc[s] + (size_t)(it + 1) * 128,       vdst + nb * 16384 + s * 1024);
      }
    }

    const char* kb0 = smem + buf * 16384;
    const char* vb0 = smem + 32768 + buf * 16384;

    // QK^T (swapped): t = S~^T tile [32 j][32 i]
    f32x16 t = {};
#pragma unroll
    for (int kc = 0; kc < 4; ++kc) {
      bf16x8 kf = *(const bf16x8*)(kb0 + swk(par * 32 + nn, kc * 32 + g * 16));
      t = __builtin_amdgcn_mfma_f32_32x32x16_bf16(kf, qf[kc], t, 0, 0, 0);
    }

    // exp2 + pack + permlane -> PV A-frags in registers
    unsigned P[8];
#pragma unroll
    for (int e = 0; e < 8; ++e) {
      float s0 = fexp2(__builtin_fmaf(t[2 * e],     C_L8, -hq));
      float s1 = fexp2(__builtin_fmaf(t[2 * e + 1], C_L8, -hq));
      P[e] = pk2(s0, s1);
    }
    asm volatile("v_permlane32_swap_b32 %0, %1" : "+v"(P[0]), "+v"(P[2]));
    asm volatile("v_permlane32_swap_b32 %0, %1" : "+v"(P[1]), "+v"(P[3]));
    asm volatile("v_permlane32_swap_b32 %0, %1" : "+v"(P[4]), "+v"(P[6]));
    asm volatile("v_permlane32_swap_b32 %0, %1" : "+v"(P[5]), "+v"(P[7]));
    u32x4v f0v = { P[0], P[1], P[2], P[3] };
    u32x4v f1v = { P[4], P[5], P[6], P[7] };
    bf16x8 af0 = __builtin_bit_cast(bf16x8, f0v);
    bf16x8 af1 = __builtin_bit_cast(bf16x8, f1v);

    // PV: acc += S~ * V~ (V~ pre-scaled by w_j in prepass)
    {
      bf16x8 v0 = *(const bf16x8*)(vb0 + swv(nn,      par * 64 + g * 16));
      bf16x8 v1 = *(const bf16x8*)(vb0 + swv(32 + nn, par * 64 + g * 16));
      acc0 = __builtin_amdgcn_mfma_f32_32x32x16_bf16(af0, v0, acc0, 0, 0, 0);
      acc1 = __builtin_amdgcn_mfma_f32_32x32x16_bf16(af0, v1, acc1, 0, 0, 0);
      v0 = *(const bf16x8*)(vb0 + swv(nn,      par * 64 + 32 + g * 16));
      v1 = *(const bf16x8*)(vb0 + swv(32 + nn, par * 64 + 32 + g * 16));
      acc0 = __builtin_amdgcn_mfma_f32_32x32x16_bf16(af1, v0, acc0, 0, 0, 0);
      acc1 = __builtin_amdgcn_mfma_f32_32x32x16_bf16(af1, v1, acc1, 0, 0, 0);
    }

    __syncthreads();   // drains vmcnt(0): next tile landed; buffers free
    buf ^= 1;
  }

  // ---- 4-parity combine via LDS, then write out
  float* xb = (float*)smem;
  if (par != 0) {
    float* dst = xb + ((par - 1) * 2 + rg) * 2048;
#pragma unroll
    for (int r = 0; r < 16; ++r) {
      dst[r * 64 + lane]        = acc0[r];
      dst[(16 + r) * 64 + lane] = acc1[r];
    }
  }
  __syncthreads();
  if (par == 0) {
    float* op = out + ((size_t)bh * LEN + qb * 64 + rg * 32) * DIM;
#pragma unroll
    for (int r = 0; r < 16; ++r) {
      const int row = (r & 3) + 8 * (r >> 2) + 4 * g;
      float a0 = acc0[r], a1 = acc1[r];
#pragma unroll
      for (int p = 1; p < 4; ++p) {
        const float* sb = xb + ((p - 1) * 2 + rg) * 2048;
        a0 += sb[r * 64 + lane];
        a1 += sb[(16 + r) * 64 + lane];
      }
      op[(size_t)row * DIM + nn]      = a0;
      op[(size_t)row * DIM + 32 + nn] = a1;
    }
  }
}

// ---------------- fallback (the round-2 passing kernel, unchanged) -----------
__device__ __forceinline__ int swfb(int row, int byte) {
  return row * 128 + (byte ^ ((row & 7) << 4));
}

__global__ __launch_bounds__(512, 2) void soft_attn_fb(
    const float* __restrict__ q, const float* __restrict__ v,
    float* __restrict__ out) {
  __shared__ __align__(16) char smem[33280];
  const int tid = threadIdx.x;
  const int lane = tid & 63;
  const int wave = tid >> 6;
  const int rg = wave & 3;
  const int parity = wave >> 2;
  const int tp = tid & 255;
  const int g = lane >> 5;
  const int nn = lane & 31;
  const int wg = ((blockIdx.x & 7) << 5) | (blockIdx.x >> 3);
  const int bh = wg >> 4;
  const int qb = wg & 15;
  const float* qh = q + (size_t)bh * LEN * DIM;
  const float* vh = v + (size_t)bh * LEN * DIM;
  char* kbufp = smem + parity * 8192;
  char* vbufp = smem + 16384 + parity * 8192;
  float* wkp = (float*)(smem + 32768) + parity * 64;
  const int qrow = qb * 128 + rg * 32 + nn;
  bf16x8 qf[4];
  float sq = 0.f;
  {
    const float* qp = qh + (size_t)qrow * DIM;
#pragma unroll
    for (int kc = 0; kc < 4; ++kc) {
      const int d0 = kc * 16 + g * 8;
      fvec4 x = *(const fvec4*)(qp + d0);
      fvec4 y = *(const fvec4*)(qp + d0 + 4);
      bf16x8 t;
#pragma unroll
      for (int e = 0; e < 4; ++e) {
        bf16_t h0 = (bf16_t)x[e]; t[e] = h0; float f0 = (float)h0; sq += f0 * f0;
        bf16_t h1 = (bf16_t)y[e]; t[e + 4] = h1; float f1 = (float)h1; sq += f1 * f1;
      }
      qf[kc] = t;
    }
  }
  sq += __shfl_xor(sq, 32);
  const float hq = sq * C_L16;
  f32x16 acc0 = {};
  f32x16 acc1 = {};
  for (int it = 0; it < 16; ++it) {
    const int jt = it * 2 + parity;
    const float* kg = qh + (size_t)jt * 64 * DIM;
    const float* vg = vh + (size_t)jt * 64 * DIM;
    __syncthreads();
#pragma unroll
    for (int s = 0; s < 2; ++s) {
      const int c = tp + 256 * s;
      const int j = c >> 3;
      const int d0 = (c & 7) * 8;
      fvec4 x = *(const fvec4*)(kg + j * DIM + d0);
      fvec4 y = *(const fvec4*)(kg + j * DIM + d0 + 4);
      bf16x8 t; float p = 0.f;
#pragma unroll
      for (int e = 0; e < 4; ++e) {
        bf16_t h0 = (bf16_t)x[e]; t[e] = h0; float f0 = (float)h0; p += f0 * f0;
        bf16_t h1 = (bf16_t)y[e]; t[e + 4] = h1; float f1 = (float)h1; p += f1 * f1;
      }
      *(bf16x8*)(kbufp + swfb(j, d0 * 2)) = t;
      p += __shfl_xor(p, 1);
      p += __shfl_xor(p, 2);
      p += __shfl_xor(p, 4);
      if ((lane & 7) == 0) wkp[j] = fexp2(-p * C_L16);
    }
    __syncthreads();
    float vl[2][8];
    const int vd = tp & 63;
    const int vw = tp >> 6;
#pragma unroll
    for (int s = 0; s < 2; ++s) {
      const int j0 = vw * 8 + 32 * s;
      const float* vp = vg + j0 * DIM + vd;
#pragma unroll
      for (int r = 0; r < 8; ++r) vl[s][r] = vp[r * DIM];
    }
    bf16x8 af[4];
#pragma unroll
    for (int jsub = 0; jsub < 2; ++jsub) {
      f32x16 t = {};
#pragma unroll
      for (int kc = 0; kc < 4; ++kc) {
        bf16x8 kf = *(const bf16x8*)(kbufp + swfb(jsub * 32 + nn, kc * 32 + g * 16));
        t = __builtin_amdgcn_mfma_f32_32x32x16_bf16(kf, qf[kc], t, 0, 0, 0);
      }
      unsigned P[8];
#pragma unroll
      for (int e = 0; e < 8; ++e) {
        float s0 = fexp2(__builtin_fmaf(t[2 * e], C_L8, -hq));
        float s1 = fexp2(__builtin_fmaf(t[2 * e + 1], C_L8, -hq));
        P[e] = pk2(s0, s1);
      }
      asm volatile("v_permlane32_swap_b32 %0, %1" : "+v"(P[0]), "+v"(P[2]));
      asm volatile("v_permlane32_swap_b32 %0, %1" : "+v"(P[1]), "+v"(P[3]));
      asm volatile("v_permlane32_swap_b32 %0, %1" : "+v"(P[4]), "+v"(P[6]));
      asm volatile("v_permlane32_swap_b32 %0, %1" : "+v"(P[5]), "+v"(P[7]));
      u32x4v f0v = { P[0], P[1], P[2], P[3] };
      u32x4v f1v = { P[4], P[5], P[6], P[7] };
      af[jsub * 2] = __builtin_bit_cast(bf16x8, f0v);
      af[jsub * 2 + 1] = __builtin_bit_cast(bf16x8, f1v);
    }
#pragma unroll
    for (int s = 0; s < 2; ++s) {
      const int j0 = vw * 8 + 32 * s;
      bf16x8 t;
#pragma unroll
      for (int r = 0; r < 8; ++r) {
        float w = wkp[j0 + r];
        t[r] = (bf16_t)(vl[s][r] * w);
      }
      *(bf16x8*)(vbufp + swfb(vd, j0 * 2)) = t;
    }
    __syncthreads();
#pragma unroll
    for (int kc = 0; kc < 4; ++kc) {
      bf16x8 v0 = *(const bf16x8*)(vbufp + swfb(nn, kc * 32 + g * 16));
      bf16x8 v1 = *(const bf16x8*)(vbufp + swfb(32 + nn, kc * 32 + g * 16));
      acc0 = __builtin_amdgcn_mfma_f32_32x32x16_bf16(af[kc], v0, acc0, 0, 0, 0);
      acc1 = __builtin_amdgcn_mfma_f32_32x32x16_bf16(af[kc], v1, acc1, 0, 0, 0);
    }
  }
  __syncthreads();
  float* xb = (float*)smem + rg * 2048;
  if (parity == 1) {
#pragma unroll
    for (int r = 0; r < 16; ++r) {
      xb[r * 64 + lane] = acc0[r];
      xb[(16 + r) * 64 + lane] = acc1[r];
    }
  }
  __syncthreads();
  if (parity == 0) {
    float* op = out + ((size_t)bh * LEN + qb * 128 + rg * 32) * DIM;
#pragma unroll
    for (int r = 0; r < 16; ++r) {
      const int row = (r & 3) + 8 * (r >> 2) + 4 * g;
      op[(size_t)row * DIM + nn] = acc0[r] + xb[r * 64 + lane];
      op[(size_t)row * DIM + 32 + nn] = acc1[r] + xb[(16 + r) * 64 + lane];
    }
  }
}

extern "C" void kernel_launch(void* const* d_in, const int* in_sizes, int n_in,
                              void* d_out, int out_size, void* d_ws, size_t ws_size,
                              hipStream_t stream) {
  const float* q = (const float*)d_in[0];
  const float* v = (const float*)d_in[1];
  float* out = (float*)d_out;
  (void)in_sizes; (void)n_in; (void)out_size;

  const size_t KB_BYTES = (size_t)NH * LEN * DIM * 2;  // 4 MiB
  const size_t NEED = KB_BYTES * 2 + (size_t)NH * LEN * 4;
  if (ws_size >= NEED) {
    bf16_t* kb  = (bf16_t*)d_ws;
    bf16_t* vt  = (bf16_t*)((char*)d_ws + KB_BYTES);
    float*  sqw = (float*)((char*)d_ws + KB_BYTES * 2);
    prepass<<<dim3(512), dim3(256), 0, stream>>>(q, v, kb, vt, sqw);
    soft_attn_main<<<dim3(512), dim3(512), 0, stream>>>(kb, vt, sqw, out);
  } else {
    soft_attn_fb<<<dim3(256), dim3(512), 0, stream>>>(q, v, out);
  }
}